// Round 5
// baseline (944.449 us; speedup 1.0000x reference)
//
#include <hip/hip_runtime.h>
#include <math.h>

// Fused Conv2d(64->128,3x3,valid) + bias + min(oc) + tanh(tanh()) via
// bf16 MFMA implicit GEMM (mfma_f32_32x32x16_bf16).
//
// Round 10 == Round 9 resubmit (container-level infra failure last round;
// kernel audited for deadlock/OOB — none found).
//
// Persistent rolling-window blocks.
//  - Each block owns up to 11 consecutive oh-pairs (grid 4 x 12 x 16 = 768
//    blocks = exactly 3/CU, LDS-capped). 6-row circular input window in LDS;
//    per iteration only the 2 NEW rows are staged (24 regs in flight),
//    issued BEFORE the 144-MFMA K-loop and consumed after its midpoint /
//    end — load latency hides under MFMA, and slot-disjointness means no
//    barrier sits between issue and consume (compiler can't defeat it).
//  - Staging traffic halves vs round 6 (2 rows/pair instead of 4).
//  - K-loop = round 6's proven rotation (A dist-1 ds_read, B dist-2 L2
//    loads), A row addressing via 3 per-iteration slot base pointers.
//  - Epilogue without the 33KB sm overlay (xt stays live): in-register
//    butterfly reduce-scatter over l31 (31 shfl_xor; lane l ends with
//    pixel bitrev5(l31)) + 1KB obuf for the cross-nh min; 2 barriers/iter.
// Block: 256 thr = 4 waves (r = w&1 row, nh = w>>1 oc-half).
// LDS: xt[6 slot][8 g][66 col][8 j] bf16 = 50688 B + obuf 1KB.

typedef __attribute__((ext_vector_type(8))) short bf16x8;
typedef __attribute__((ext_vector_type(16))) float f32x16;

static __device__ __forceinline__ short f2bf(float f) {
    unsigned u = __float_as_uint(f);
    u += 0x7fffu + ((u >> 16) & 1u);
    return (short)(u >> 16);
}

// v_cvt_pk_bf16_f32: D[15:0]=bf16(a), D[31:16]=bf16(b), round-nearest-even.
static __device__ __forceinline__ unsigned cvt_pk_bf16(float a, float b) {
    unsigned r;
    asm("v_cvt_pk_bf16_f32 %0, %1, %2" : "=v"(r) : "v"(a), "v"(b));
    return r;
}

// d_ws layout: bf16 bits, idx = ((kstep*2 + hi)*128 + oc)*8 + j
// kstep = tap*4 + icc, tap = kh*3 + kw, ic = icc*16 + hi*8 + j. 73728 elems.
__global__ void wtrans(const float* __restrict__ wg, short* __restrict__ wsB) {
    int o4 = blockIdx.x * 256 + threadIdx.x;   // 0..18431 (x4 elements)
    if (o4 >= 18432) return;
    float4 v = ((const float4*)wg)[o4];        // coalesced read
    float f[4] = {v.x, v.y, v.z, v.w};
    int base = o4 * 4;
    #pragma unroll
    for (int q = 0; q < 4; ++q) {
        int e  = base + q;                     // ((oc*64+ic)*3+kh)*3+kw
        int kw = e % 3, r1 = e / 3;
        int kh = r1 % 3, r2 = r1 / 3;
        int ic = r2 & 63, oc = r2 >> 6;
        int tap = kh * 3 + kw;
        int icc = ic >> 4, hi = (ic >> 3) & 1, j = ic & 7;
        int kstep = tap * 4 + icc;
        wsB[((kstep * 2 + hi) * 128 + oc) * 8 + j] = f2bf(f[q]);
    }
}

// Stage ONE input row (global row rg): 8 g-groups x 66 cols = 528 bf16x8.
// Per thread <= 3 batches of 8 floats (24 regs in flight).
#define STAGE1_ISSUE(rg, fbuf)                                                \
    _Pragma("unroll")                                                         \
    for (int s = 0; s < 3; ++s) {                                             \
        int idx = s * 256 + tid;                                              \
        if (idx < 528) {                                                      \
            int g = idx / 66, col = idx - g * 66;                             \
            int icc = g >> 1, hie = g & 1;                                    \
            int iw = ow0 + col;                                               \
            const float* src = xg +                                           \
                (((size_t)(b * 64 + icc * 16 + hie * 8) * 256) + (rg)) * 256 + iw; \
            bool valid = iw < 256;                                            \
            _Pragma("unroll")                                                 \
            for (int j = 0; j < 8; ++j) fbuf[s][j] = valid ? src[j * 65536] : 0.f; \
        }                                                                     \
    }

#define STAGE1_WRITE(ss, fbuf)                                                \
    _Pragma("unroll")                                                         \
    for (int s = 0; s < 3; ++s) {                                             \
        int idx = s * 256 + tid;                                              \
        if (idx < 528) {                                                      \
            int g = idx / 66, col = idx - g * 66;                             \
            int icc = g >> 1, hie = g & 1;                                    \
            bf16x8 vv;                                                        \
            unsigned* vp = (unsigned*)&vv;                                    \
            _Pragma("unroll")                                                 \
            for (int p = 0; p < 4; ++p)                                       \
                vp[p] = cvt_pk_bf16(fbuf[s][2 * p], fbuf[s][2 * p + 1]);      \
            *(bf16x8*)(xt + ((ss) * 8 + icc * 2 + hie) * 528 + col * 8) = vv; \
        }                                                                     \
    }

__global__ __launch_bounds__(256, 3)
void conv_min_tanh_mfma(const float* __restrict__ xg,
                        const short* __restrict__ wsB,
                        const float* __restrict__ bg,
                        float* __restrict__ out) {
    __shared__ __align__(16) short xt[25344];  // 6 slots x 8 g x 528 = 50688 B
    __shared__ float obuf[256];                // [2 nh][128 px]

    const int tid  = threadIdx.x;
    const int lane = tid & 63, l31 = lane & 31, hi = lane >> 5;
    const int w    = tid >> 6;
    const int r    = w & 1;        // output row within pair
    const int nh   = w >> 1;       // oc half
    const int ow0  = blockIdx.x * 64;
    const int b    = blockIdx.z;
    const int p0   = blockIdx.y * 11;          // first oh-pair
    const int np   = min(11, 127 - p0);        // pairs this block owns
    const int ih0  = p0 * 2;                   // first input row

    // ---- B pipeline prime (k=0, k=1); L2-resident, hides under prologue.
    const bf16x8* bbase = (const bf16x8*)(wsB + ((size_t)hi * 128 + nh * 64 + l31) * 8);
    bf16x8 bc0 = bbase[0],   bc1 = bbase[32];
    bf16x8 bd0 = bbase[256], bd1 = bbase[256 + 32];

    // ---- prologue: stage input rows ih0..ih0+3 -> slots 0..3
    {
        float fP[3][8], fQ[3][8];
        STAGE1_ISSUE(ih0 + 0, fP)
        STAGE1_ISSUE(ih0 + 1, fQ)
        STAGE1_WRITE(0, fP)
        STAGE1_WRITE(1, fQ)
        STAGE1_ISSUE(ih0 + 2, fP)
        STAGE1_ISSUE(ih0 + 3, fQ)
        STAGE1_WRITE(2, fP)
        STAGE1_WRITE(3, fQ)
    }
    const float bv0 = bg[nh * 64 + l31];
    const float bv1 = bg[nh * 64 + 32 + l31];
    __syncthreads();

    int s0 = r, s1 = r + 1, s2 = r + 2;  // A row slots for kh=0,1,2 (this wave)
    int sA = 4, sB = 5;                  // stage destination slots
    float fS[3][8];

    for (int it = 0; it < np; ++it) {
        const bool do_stage = (it < np - 1);
        // issue loads for input row 2it+4 (consumed at K-loop midpoint)
        if (do_stage) { STAGE1_ISSUE(ih0 + 2 * it + 4, fS) }

        const bf16x8* bp0 = (const bf16x8*)(xt + (s0 * 8 + hi) * 528 + l31 * 8);
        const bf16x8* bp1 = (const bf16x8*)(xt + (s1 * 8 + hi) * 528 + l31 * 8);
        const bf16x8* bp2 = (const bf16x8*)(xt + (s2 * 8 + hi) * 528 + l31 * 8);

        f32x16 acc00 = {}, acc01 = {}, acc10 = {}, acc11 = {};
        bf16x8 a0 = bp0[0], a1 = bp0[32];      // k=0 (tap0, icc0)

        #pragma unroll
        for (int k = 0; k < 36; ++k) {
            if (k == 18) {
                // write row 2it+4 (slot sA disjoint from read slots s0..s2+1),
                // then issue loads for row 2it+5 (consumed after the loop).
                if (do_stage) {
                    STAGE1_WRITE(sA, fS)
                    STAGE1_ISSUE(ih0 + 2 * it + 5, fS)
                }
            }
            // A prefetch for k+1 (2 ds_read_b128)
            bf16x8 an0 = a0, an1 = a1;
            if (k < 35) {
                const int kn = k + 1, tapn = kn >> 2, iccn = kn & 3;
                const int khn = tapn / 3, kwn = tapn - khn * 3;
                const bf16x8* bp = (khn == 0) ? bp0 : (khn == 1) ? bp1 : bp2;
                an0 = bp[iccn * 132 + kwn];
                an1 = bp[iccn * 132 + kwn + 32];
            }
            // B prefetch distance 2
            bf16x8 be0 = bd0, be1 = bd1;
            if (k < 34) {
                be0 = bbase[(k + 2) * 256];
                be1 = bbase[(k + 2) * 256 + 32];
            }
            acc00 = __builtin_amdgcn_mfma_f32_32x32x16_bf16(a0, bc0, acc00, 0, 0, 0);
            acc01 = __builtin_amdgcn_mfma_f32_32x32x16_bf16(a0, bc1, acc01, 0, 0, 0);
            acc10 = __builtin_amdgcn_mfma_f32_32x32x16_bf16(a1, bc0, acc10, 0, 0, 0);
            acc11 = __builtin_amdgcn_mfma_f32_32x32x16_bf16(a1, bc1, acc11, 0, 0, 0);
            a0 = an0; a1 = an1;
            bc0 = bd0; bc1 = bd1;
            bd0 = be0; bd1 = be1;
        }

        // write row 2it+5 (slot sB, disjoint from all read slots)
        if (do_stage) { STAGE1_WRITE(sB, fS) }
        // re-prime B pipeline for next iteration (L1-resident)
        bc0 = bbase[0];   bc1 = bbase[32];
        bd0 = bbase[256]; bd1 = bbase[256 + 32];

        __syncthreads();   // new rows visible; obuf safe to write

        // ---- epilogue: bias + oc-pair min, butterfly reduce over l31
        float v[32];
        #pragma unroll
        for (int reg = 0; reg < 16; ++reg) {
            v[reg]      = fminf(acc00[reg] + bv0, acc01[reg] + bv1);  // m-tile 0
            v[16 + reg] = fminf(acc10[reg] + bv0, acc11[reg] + bv1);  // m-tile 1
        }
        #pragma unroll
        for (int mbit = 1; mbit <= 16; mbit <<= 1) {
            const int cnt = 16 / mbit;
            bool up = (l31 & mbit) != 0;
            #pragma unroll
            for (int j = 0; j < cnt; ++j) {
                float send = up ? v[j] : v[j + cnt];
                float recv = __shfl_xor(send, mbit, 64);
                float mine = up ? v[j + cnt] : v[j];
                v[j] = fminf(mine, recv);
            }
        }
        // lane l31 holds the reduced value for index ridx = bitrev5(l31):
        // tile = ridx>>4, reg = ridx&15, m = (reg&3)+8*(reg>>2)+4*hi
        {
            int ridx = ((l31 & 1) << 4) | ((l31 & 2) << 2) | (l31 & 4) |
                       ((l31 & 8) >> 2) | ((l31 & 16) >> 4);
            int mm = ridx & 15;
            int px = ((ridx >> 4) << 5) + (mm & 3) + ((mm >> 2) << 3) + (hi << 2);
            obuf[nh * 128 + r * 64 + px] = v[0];
        }
        __syncthreads();

        if (tid < 128) {
            float x = fminf(obuf[tid], obuf[128 + tid]);
            x = tanhf(tanhf(x));
            const int col = tid & 63, row = tid >> 6;
            const int oh = (p0 + it) * 2 + row;
            if (ow0 + col < 254)
                out[((size_t)b * 254 + oh) * 254 + ow0 + col] = x;
        }

        // advance circular slots by 2 rows
        s0 += 2; if (s0 >= 6) s0 -= 6;
        s1 += 2; if (s1 >= 6) s1 -= 6;
        s2 += 2; if (s2 >= 6) s2 -= 6;
        sA += 2; if (sA >= 6) sA -= 6;
        sB += 2; if (sB >= 6) sB -= 6;
    }
}

extern "C" void kernel_launch(void* const* d_in, const int* in_sizes, int n_in,
                              void* d_out, int out_size, void* d_ws, size_t ws_size,
                              hipStream_t stream) {
    const float* x  = (const float*)d_in[0];   // (16,64,256,256)
    const float* wg = (const float*)d_in[1];   // (128,64,3,3)
    const float* bs = (const float*)d_in[2];   // (128,)
    float* out = (float*)d_out;                // (16,1,254,254)
    short* wsB = (short*)d_ws;                 // needs 147456 B

    wtrans<<<72, 256, 0, stream>>>(wg, wsB);
    dim3 grid(4, 12, 16);   // ow tiles, oh-pair groups (11 pairs each), batch
    conv_min_tanh_mfma<<<grid, 256, 0, stream>>>(x, wsB, bs, out);
}